// Round 2
// baseline (2127.078 us; speedup 1.0000x reference)
//
#include <hip/hip_runtime.h>
#include <stdint.h>

#define BB 256
#define TT 128
#define DD 512
#define HH 512
#define G4 2048      // 4H
#define KT 1024      // D + H
#define BH (BB*HH)   // 131072

typedef short bf16x8 __attribute__((ext_vector_type(8)));
typedef float f32x4  __attribute__((ext_vector_type(4)));

__device__ __forceinline__ unsigned short f2bf(float f){
  union { float f; unsigned u; } v; v.f = f;
  unsigned u = v.u;
  unsigned r = (u + 0x7FFFu + ((u >> 16) & 1u)) >> 16;
  return (unsigned short)r;
}

// x [B,T,D] f32 -> xtr [T,B,D] bf16
__global__ void prep_x_k(const float* __restrict__ x, unsigned short* __restrict__ xtr){
  const int n4 = BB*TT*(DD/4);
  for (int i = blockIdx.x*blockDim.x + threadIdx.x; i < n4; i += gridDim.x*blockDim.x){
    int d4 = i & (DD/4 - 1);
    int b  = (i / (DD/4)) & (BB-1);
    int t  = i / ((DD/4)*BB);
    float4 v = *(const float4*)(x + (((size_t)b*TT + t)*DD + (size_t)d4*4));
    ushort4 o;
    o.x = f2bf(v.x); o.y = f2bf(v.y); o.z = f2bf(v.z); o.w = f2bf(v.w);
    *(ushort4*)(xtr + (((size_t)t*BB + b)*DD + (size_t)d4*4)) = o;
  }
}

// Wcat_t[dir][n'][k]: n' = hb*64 + g*16 + j  <->  orig col n = g*512 + hb*16 + j
__global__ void prep_w_k(const float* __restrict__ Wf, const float* __restrict__ Uf,
                         const float* __restrict__ Wb, const float* __restrict__ Ub,
                         unsigned short* __restrict__ wcat){
  const int tot = 2*G4*KT;  // 4M
  for (int i = blockIdx.x*blockDim.x + threadIdx.x; i < tot; i += gridDim.x*blockDim.x){
    int k   = i & (KT-1);
    int np  = (i >> 10) & (G4-1);
    int dir = i >> 21;
    int j  = np & 15;
    int g  = (np >> 4) & 3;
    int hb = np >> 6;
    int n  = g*HH + hb*16 + j;
    const float* W = dir ? Wb : Wf;
    const float* U = dir ? Ub : Uf;
    float v = (k < DD) ? W[(size_t)k*G4 + n] : U[(size_t)(k-DD)*G4 + n];
    wcat[i] = f2bf(v);
  }
}

__global__ void prep_bias_k(const float* __restrict__ bf_, const float* __restrict__ bb_,
                            float* __restrict__ bias_sw){
  int i = blockIdx.x*blockDim.x + threadIdx.x;
  if (i < 2*G4){
    int np  = i & (G4-1);
    int dir = i >> 11;
    int j = np & 15, g = (np>>4)&3, hb = np>>6;
    const float* src = dir ? bb_ : bf_;
    bias_sw[i] = src[g*HH + hb*16 + j];
  }
}

// Persistent bidirectional LSTM. 256 blocks x 256 threads, 1 block/CU.
// block: dir = bid>>7, mb = (bid>>5)&3 (64 batch rows), hb = bid&31 (16 h cols x 4 gates).
// Weights for this block's 64 output cols stay in LDS (128KB) for all 128 steps.
// Sync: monotonic agent-scope counter per (dir,mb) group of 32 blocks.
__global__ __launch_bounds__(256, 1)
void lstm_persist_k(const unsigned short* __restrict__ xtr,
                    const unsigned short* __restrict__ wcat,
                    const float* __restrict__ bias_sw,
                    unsigned short* hbf,
                    int* cnt,
                    float* __restrict__ out)
{
  __shared__ __align__(1024) unsigned short Bl[64*KT];     // 128KB persistent weights
  __shared__ __align__(1024) unsigned short Al[2][64*64];  // 16KB A-chunk double buffer

  const int tid  = threadIdx.x;
  const int lane = tid & 63;
  const int w    = tid >> 6;
  const int bid  = blockIdx.x;
  const int dir  = bid >> 7;
  const int mb   = (bid >> 5) & 3;
  const int hb   = bid & 31;
  const int m0   = mb * 64;
  const int n0   = hb * 64;

  // ---- load persistent B tile (64 rows x 1024 k), XOR-swizzled source ----
  const unsigned short* wb2 = wcat + (size_t)dir*G4*KT + (size_t)n0*KT;
  for (int it = 0; it < 32; ++it){
    int u   = it*256 + tid;          // 16B unit index in 128KB tile
    int row = u >> 7, un = u & 127;
    int su  = (un & ~7) | ((un & 7) ^ (row & 7));
    __builtin_amdgcn_global_load_lds(
      (const __attribute__((address_space(1))) void*)(wb2 + (size_t)row*KT + su*8),
      (__attribute__((address_space(3))) void*)(Bl + u*8), 16, 0, 0);
  }

  const int jl = lane & 15;
  const int q  = lane >> 4;
  const int j  = (hb << 4) + jl;
  const int rowA = (w << 4) + jl;
  const float* biasd = bias_sw + dir*G4 + n0;
  const float bi0 = biasd[jl];
  const float bi1 = biasd[16 + jl];
  const float bi2 = biasd[32 + jl];
  const float bi3 = biasd[48 + jl];
  float cst[4] = {0.f, 0.f, 0.f, 0.f};
  int* mycnt = cnt + dir*4 + mb;

  __syncthreads();   // B staged (barrier drains vmcnt)

  for (int s = 0; s < TT; ++s){
    const int t = dir ? (TT-1-s) : s;
    const unsigned short* xt  = xtr + (size_t)t*BB*DD + (size_t)m0*DD;
    const unsigned short* hin = hbf + (size_t)((s&1)*2 + dir)*BH + (size_t)m0*HH;
    unsigned short*      hout = hbf + (size_t)(((s&1)^1)*2 + dir)*BH;

    f32x4 acc[4];
    #pragma unroll
    for (int f = 0; f < 4; ++f) acc[f] = (f32x4){0.f,0.f,0.f,0.f};

    auto stage_x = [&](int kc, int bufi){
      const unsigned short* asrc = xt + (size_t)kc*64;
      #pragma unroll
      for (int i = 0; i < 2; ++i){
        int u = (w*2 + i)*64 + lane;
        int row = u >> 3, uu = u & 7;
        int su  = uu ^ (row & 7);
        __builtin_amdgcn_global_load_lds(
          (const __attribute__((address_space(1))) void*)(asrc + (size_t)row*DD + su*8),
          (__attribute__((address_space(3))) void*)(Al[bufi] + u*8), 16, 0, 0);
      }
    };
    // h staged via agent-scope atomic loads (coherent across XCDs) -> ds_write
    auto stage_h = [&](int kc, int bufi){
      const unsigned short* hsrc = hin + (size_t)(kc-8)*64;
      #pragma unroll
      for (int i = 0; i < 2; ++i){
        int u = (w*2 + i)*64 + lane;
        int row = u >> 3, uu = u & 7;
        int su  = uu ^ (row & 7);
        unsigned long long* p = (unsigned long long*)(hsrc + (size_t)row*HH + su*8);
        unsigned long long v0 = __hip_atomic_load(p,     __ATOMIC_RELAXED, __HIP_MEMORY_SCOPE_AGENT);
        unsigned long long v1 = __hip_atomic_load(p + 1, __ATOMIC_RELAXED, __HIP_MEMORY_SCOPE_AGENT);
        unsigned long long* ld = (unsigned long long*)(Al[bufi] + u*8);
        ld[0] = v0; ld[1] = v1;
      }
    };
    auto compute = [&](int kc, int bufi){
      const unsigned short* A = Al[bufi];
      #pragma unroll
      for (int kk = 0; kk < 2; ++kk){
        int unl = kk*4 + q;
        bf16x8 a = *(const bf16x8*)(A + rowA*64 + ((unl ^ (rowA & 7)) << 3));
        #pragma unroll
        for (int f = 0; f < 4; ++f){
          int rowB = (f << 4) + jl;
          const unsigned short* bp = Bl + (size_t)rowB*KT + kc*64 + ((unl ^ (rowB & 7)) << 3);
          acc[f] = __builtin_amdgcn_mfma_f32_16x16x32_bf16(a, *(const bf16x8*)bp, acc[f], 0, 0, 0);
        }
      }
    };

    // ---- x phase: chunks 0..7 (no h dependency — overlaps group sync) ----
    stage_x(0, 0);
    __syncthreads();
    for (int kc = 0; kc < 8; ++kc){
      if (kc < 7) stage_x(kc+1, (kc+1) & 1);
      compute(kc, kc & 1);
      __syncthreads();
    }

    // ---- wait for group to finish step s-1 (h[s] ready) ----
    if (tid == 0){
      const int target = 32*s;
      while (__hip_atomic_load(mycnt, __ATOMIC_RELAXED, __HIP_MEMORY_SCOPE_AGENT) < target) {}
    }
    __syncthreads();

    // ---- h phase: chunks 8..15 ----
    stage_h(8, 0);
    __syncthreads();
    for (int kc = 8; kc < 16; ++kc){
      if (kc < 15) stage_h(kc+1, (kc+1-8) & 1);
      compute(kc, (kc-8) & 1);
      __syncthreads();
    }

    // ---- epilogue: gates, c in registers, h + out stores ----
    #pragma unroll
    for (int rr = 0; rr < 4; ++rr){
      int brow = m0 + (w<<4) + (q<<2) + rr;
      float zi = acc[0][rr] + bi0;
      float zf = acc[1][rr] + bi1;
      float zg = acc[2][rr] + bi2;
      float zo = acc[3][rr] + bi3;
      float ig = 1.0f/(1.0f + __expf(-zi));
      float fg = 1.0f/(1.0f + __expf(-zf));
      float gg = tanhf(zg);
      float og = 1.0f/(1.0f + __expf(-zo));
      float c  = fg*cst[rr] + ig*gg;
      cst[rr]  = c;
      float h  = og * tanhf(c);
      out[((size_t)brow*TT + t)*(2*HH) + (size_t)dir*HH + j] = h;
      unsigned short hb16 = f2bf(h);
      int other = __shfl_xor((int)hb16, 1);
      if (!(jl & 1)){
        unsigned int pack = (unsigned int)hb16 | (((unsigned int)other & 0xFFFFu) << 16);
        __hip_atomic_store((unsigned int*)(hout + (size_t)brow*HH + (j & ~1)),
                           pack, __ATOMIC_RELAXED, __HIP_MEMORY_SCOPE_AGENT);
      }
    }

    __syncthreads();   // drain all waves' h stores (vmcnt) before signaling
    if (tid == 0)
      (void)__hip_atomic_fetch_add(mycnt, 1, __ATOMIC_RELEASE, __HIP_MEMORY_SCOPE_AGENT);
  }
}

// sent_emb[b][n] = word_emb[b][T-1][n] (n<H) or word_emb[b][0][n] (n>=H)
__global__ void final_k(float* __restrict__ out){
  int i = blockIdx.x*blockDim.x + threadIdx.x;
  if (i < BB*2*HH){
    int b = i >> 10;
    int n = i & 1023;
    int t = (n < HH) ? (TT-1) : 0;
    out[(size_t)BB*TT*2*HH + i] = out[((size_t)b*TT + t)*2*HH + n];
  }
}

extern "C" void kernel_launch(void* const* d_in, const int* in_sizes, int n_in,
                              void* d_out, int out_size, void* d_ws, size_t ws_size,
                              hipStream_t stream)
{
  const float* x   = (const float*)d_in[0];
  const float* Wf  = (const float*)d_in[1];
  const float* Uf  = (const float*)d_in[2];
  const float* bf_ = (const float*)d_in[3];
  const float* Wb  = (const float*)d_in[4];
  const float* Ub  = (const float*)d_in[5];
  const float* bb_ = (const float*)d_in[6];
  float* out = (float*)d_out;

  char* ws = (char*)d_ws;
  unsigned short* xtr  = (unsigned short*)ws;                          // 33,554,432 B
  unsigned short* wcat = (unsigned short*)(ws + 33554432);             //  8,388,608 B
  float* bias_sw       = (float*)(ws + 41943040);                      //     16,384 B
  unsigned short* hbf  = (unsigned short*)(ws + 41959424);             //  1,048,576 B (2 parity x 2 dir x B*H bf16)
  int* cnt             = (int*)(ws + 43008000);                        //         32 B

  hipMemsetAsync(hbf, 0, (size_t)2*BH*2, stream);   // parity-0 h buffers (both dirs) = 0
  hipMemsetAsync(cnt, 0, 32, stream);

  prep_x_k   <<<2048, 256, 0, stream>>>(x, xtr);
  prep_w_k   <<<4096, 256, 0, stream>>>(Wf, Uf, Wb, Ub, wcat);
  prep_bias_k<<<16,   256, 0, stream>>>(bf_, bb_, bias_sw);

  void* kargs[] = {(void*)&xtr, (void*)&wcat, (void*)&bias_sw,
                   (void*)&hbf, (void*)&cnt, (void*)&out};
  hipLaunchCooperativeKernel((const void*)lstm_persist_k, dim3(256), dim3(256),
                             kargs, 0, stream);

  final_k<<<1024, 256, 0, stream>>>(out);
}

// Round 3
// 1700.465 us; speedup vs baseline: 1.2509x; 1.2509x over previous
//
#include <hip/hip_runtime.h>
#include <stdint.h>

#define BB 256
#define TT 128
#define DD 512
#define HH 512
#define G4 2048      // 4H
#define KT 1024      // D + H
#define BH (BB*HH)   // 131072

typedef short bf16x8 __attribute__((ext_vector_type(8)));
typedef float f32x4  __attribute__((ext_vector_type(4)));

__device__ __forceinline__ unsigned short f2bf(float f){
  union { float f; unsigned u; } v; v.f = f;
  unsigned u = v.u;
  unsigned r = (u + 0x7FFFu + ((u >> 16) & 1u)) >> 16;
  return (unsigned short)r;
}

// x [B,T,D] f32 -> xtr [T,B,D] bf16
__global__ void prep_x_k(const float* __restrict__ x, unsigned short* __restrict__ xtr){
  const int n4 = BB*TT*(DD/4);
  for (int i = blockIdx.x*blockDim.x + threadIdx.x; i < n4; i += gridDim.x*blockDim.x){
    int d4 = i & (DD/4 - 1);
    int b  = (i / (DD/4)) & (BB-1);
    int t  = i / ((DD/4)*BB);
    float4 v = *(const float4*)(x + (((size_t)b*TT + t)*DD + (size_t)d4*4));
    ushort4 o;
    o.x = f2bf(v.x); o.y = f2bf(v.y); o.z = f2bf(v.z); o.w = f2bf(v.w);
    *(ushort4*)(xtr + (((size_t)t*BB + b)*DD + (size_t)d4*4)) = o;
  }
}

// Wcat_t[dir][n'][k]: n' = hb*64 + g*16 + j  <->  orig col n = g*512 + hb*16 + j
__global__ void prep_w_k(const float* __restrict__ Wf, const float* __restrict__ Uf,
                         const float* __restrict__ Wb, const float* __restrict__ Ub,
                         unsigned short* __restrict__ wcat){
  const int tot = 2*G4*KT;  // 4M
  for (int i = blockIdx.x*blockDim.x + threadIdx.x; i < tot; i += gridDim.x*blockDim.x){
    int k   = i & (KT-1);
    int np  = (i >> 10) & (G4-1);
    int dir = i >> 21;
    int j  = np & 15;
    int g  = (np >> 4) & 3;
    int hb = np >> 6;
    int n  = g*HH + hb*16 + j;
    const float* W = dir ? Wb : Wf;
    const float* U = dir ? Ub : Uf;
    float v = (k < DD) ? W[(size_t)k*G4 + n] : U[(size_t)(k-DD)*G4 + n];
    wcat[i] = f2bf(v);
  }
}

__global__ void prep_bias_k(const float* __restrict__ bf_, const float* __restrict__ bb_,
                            float* __restrict__ bias_sw){
  int i = blockIdx.x*blockDim.x + threadIdx.x;
  if (i < 2*G4){
    int np  = i & (G4-1);
    int dir = i >> 11;
    int j = np & 15, g = (np>>4)&3, hb = np>>6;
    const float* src = dir ? bb_ : bf_;
    bias_sw[i] = src[g*HH + hb*16 + j];
  }
}

// Persistent bidirectional LSTM with wave specialization.
// 256 blocks x 512 threads (8 waves), 1 block/CU.
// block: dir = bid>>7, mb = (bid>>5)&3 (64 batch rows), hb = bid&31 (64 gate-cols).
// Waves 0-3 (x-role): K<512 partial (x.W) -> LDS; never blocked by recurrence.
// Waves 4-7 (h-role): spin for h[s-1], K>=512 (h.U), add partial, epilogue, signal.
// Chain = (dir,mb): 32 blocks, counter target 128*s (4 h-wave signals per block).
__global__ __launch_bounds__(512, 2)
void lstm_persist_k(const unsigned short* __restrict__ xtr,
                    const unsigned short* __restrict__ wcat,
                    const float* __restrict__ bias_sw,
                    unsigned short* hbf,
                    int* cnt,
                    float* __restrict__ out)
{
  __shared__ __align__(1024) unsigned short Bl[64*KT];  // 128KB persistent weights
  __shared__ __align__(1024) float Pl[64*64];           // 16KB x-partial handoff

  const int tid  = threadIdx.x;
  const int lane = tid & 63;
  const int w    = tid >> 6;          // 0..7
  const int bid  = blockIdx.x;
  const int dir  = bid >> 7;
  const int mb   = (bid >> 5) & 3;
  const int hb   = bid & 31;
  const int m0   = mb * 64;
  const int n0   = hb * 64;
  const bool xrole = (w < 4);
  const int rw   = (w & 3) << 4;      // row base within the 64-row tile
  const int jl   = lane & 15;
  const int q    = lane >> 4;

  // ---- load persistent B tile (64 n' rows x 1024 k), XOR-swizzled source ----
  const unsigned short* wb2 = wcat + (size_t)dir*G4*KT + (size_t)n0*KT;
  for (int it = 0; it < 16; ++it){
    int u   = it*512 + tid;           // 16B unit index in 128KB tile (8192 units)
    int row = u >> 7, un = u & 127;
    int su  = (un & ~7) | ((un & 7) ^ (row & 7));
    __builtin_amdgcn_global_load_lds(
      (const __attribute__((address_space(1))) void*)(wb2 + (size_t)row*KT + su*8),
      (__attribute__((address_space(3))) void*)(Bl + u*8), 16, 0, 0);
  }

  const float* biasd = bias_sw + dir*G4 + n0;
  const float bi0 = biasd[jl];
  const float bi1 = biasd[16 + jl];
  const float bi2 = biasd[32 + jl];
  const float bi3 = biasd[48 + jl];
  float cst[4] = {0.f, 0.f, 0.f, 0.f};
  int* mycnt = cnt + (dir*4 + mb)*32;   // 128B-padded chain counters

  __syncthreads();   // weights staged (barrier drains vmcnt)

  for (int s = 0; s < TT; ++s){
    const int t = dir ? (TT-1-s) : s;

    if (xrole){
      // ---------- x partial: z_x = x_t . W  (k = 0..511) ----------
      const unsigned short* xbase =
          xtr + ((size_t)t*BB + (m0 + rw + jl))*DD + (size_t)q*8;
      bf16x8 xf[16];
      #pragma unroll
      for (int kk = 0; kk < 16; ++kk)
        xf[kk] = *(const bf16x8*)(xbase + kk*32);

      f32x4 acc[4];
      #pragma unroll
      for (int f = 0; f < 4; ++f) acc[f] = (f32x4){0.f,0.f,0.f,0.f};

      #pragma unroll
      for (int kk = 0; kk < 16; ++kk){
        const int ku = kk*4 + q;                 // 16B unit along K (0..63)
        #pragma unroll
        for (int f = 0; f < 4; ++f){
          const int rowB = (f << 4) + jl;
          const int sw = (ku & ~7) | ((ku & 7) ^ (rowB & 7));
          bf16x8 bfr = *(const bf16x8*)(Bl + (size_t)rowB*KT + sw*8);
          acc[f] = __builtin_amdgcn_mfma_f32_16x16x32_bf16(xf[kk], bfr, acc[f], 0, 0, 0);
        }
      }

      __syncthreads();   // BARRIER1: h-waves done reading Pl(s-1)
      #pragma unroll
      for (int f = 0; f < 4; ++f){
        #pragma unroll
        for (int rr = 0; rr < 4; ++rr){
          const int row64 = rw + q*4 + rr;
          const int col   = (f << 4) + jl;
          Pl[row64*64 + (col ^ (q << 4))] = acc[f][rr];
        }
      }
      __syncthreads();   // BARRIER2: Pl(s) published
    } else {
      // ---------- h partial: z_h = h[s-1] . U  (k = 512..1023) ----------
      const int target = 128*s;
      if (target > 0){
        while (__hip_atomic_load(mycnt, __ATOMIC_RELAXED, __HIP_MEMORY_SCOPE_AGENT) < target) {}
      }
      asm volatile("" ::: "memory");   // no hoisting of h loads above the spin

      unsigned long long* hsrc = (unsigned long long*)
          (hbf + (size_t)((s&1)*2 + dir)*BH + (size_t)(m0 + rw + jl)*HH + (size_t)q*8);
      unsigned long long hfA[16], hfB[16];
      #pragma unroll
      for (int kk = 0; kk < 16; ++kk){
        unsigned long long* p = (unsigned long long*)((unsigned short*)hsrc + kk*32);
        hfA[kk] = __hip_atomic_load(p,     __ATOMIC_RELAXED, __HIP_MEMORY_SCOPE_AGENT);
        hfB[kk] = __hip_atomic_load(p + 1, __ATOMIC_RELAXED, __HIP_MEMORY_SCOPE_AGENT);
      }

      f32x4 acc[4];
      #pragma unroll
      for (int f = 0; f < 4; ++f) acc[f] = (f32x4){0.f,0.f,0.f,0.f};

      #pragma unroll
      for (int kk = 0; kk < 16; ++kk){
        union { unsigned long long u[2]; bf16x8 v; } af;
        af.u[0] = hfA[kk]; af.u[1] = hfB[kk];
        const int ku = 64 + kk*4 + q;            // 16B unit along K (64..127)
        #pragma unroll
        for (int f = 0; f < 4; ++f){
          const int rowB = (f << 4) + jl;
          const int sw = (ku & ~7) | ((ku & 7) ^ (rowB & 7));
          bf16x8 bfr = *(const bf16x8*)(Bl + (size_t)rowB*KT + sw*8);
          acc[f] = __builtin_amdgcn_mfma_f32_16x16x32_bf16(af.v, bfr, acc[f], 0, 0, 0);
        }
      }

      __syncthreads();   // BARRIER1
      __syncthreads();   // BARRIER2: Pl(s) ready

      unsigned short* hout = hbf + (size_t)(((s&1)^1)*2 + dir)*BH;
      const int j = (hb << 4) + jl;
      #pragma unroll
      for (int rr = 0; rr < 4; ++rr){
        const int row64 = rw + q*4 + rr;
        const int brow  = m0 + row64;
        float zi = acc[0][rr] + Pl[row64*64 + (( 0 + jl) ^ (q << 4))] + bi0;
        float zf = acc[1][rr] + Pl[row64*64 + ((16 + jl) ^ (q << 4))] + bi1;
        float zg = acc[2][rr] + Pl[row64*64 + ((32 + jl) ^ (q << 4))] + bi2;
        float zo = acc[3][rr] + Pl[row64*64 + ((48 + jl) ^ (q << 4))] + bi3;
        float ig = 1.0f/(1.0f + __expf(-zi));
        float fg = 1.0f/(1.0f + __expf(-zf));
        float gg = tanhf(zg);
        float og = 1.0f/(1.0f + __expf(-zo));
        float c  = fg*cst[rr] + ig*gg;
        cst[rr]  = c;
        float h  = og * tanhf(c);
        out[((size_t)brow*TT + t)*(2*HH) + (size_t)dir*HH + j] = h;
        unsigned short hb16 = f2bf(h);
        int other = __shfl_xor((int)hb16, 1);
        if (!(jl & 1)){
          unsigned int pack = (unsigned int)hb16 | (((unsigned int)other & 0xFFFFu) << 16);
          __hip_atomic_store((unsigned int*)(hout + (size_t)brow*HH + (j & ~1)),
                             pack, __ATOMIC_RELAXED, __HIP_MEMORY_SCOPE_AGENT);
        }
      }

      asm volatile("s_waitcnt vmcnt(0)" ::: "memory");  // h stores at coherence point
      if (lane == 0)
        (void)__hip_atomic_fetch_add(mycnt, 1, __ATOMIC_RELAXED, __HIP_MEMORY_SCOPE_AGENT);
    }
  }
}

// sent_emb[b][n] = word_emb[b][T-1][n] (n<H) or word_emb[b][0][n] (n>=H)
__global__ void final_k(float* __restrict__ out){
  int i = blockIdx.x*blockDim.x + threadIdx.x;
  if (i < BB*2*HH){
    int b = i >> 10;
    int n = i & 1023;
    int t = (n < HH) ? (TT-1) : 0;
    out[(size_t)BB*TT*2*HH + i] = out[((size_t)b*TT + t)*2*HH + n];
  }
}

extern "C" void kernel_launch(void* const* d_in, const int* in_sizes, int n_in,
                              void* d_out, int out_size, void* d_ws, size_t ws_size,
                              hipStream_t stream)
{
  const float* x   = (const float*)d_in[0];
  const float* Wf  = (const float*)d_in[1];
  const float* Uf  = (const float*)d_in[2];
  const float* bf_ = (const float*)d_in[3];
  const float* Wb  = (const float*)d_in[4];
  const float* Ub  = (const float*)d_in[5];
  const float* bb_ = (const float*)d_in[6];
  float* out = (float*)d_out;

  char* ws = (char*)d_ws;
  unsigned short* xtr  = (unsigned short*)ws;                  // 33,554,432 B
  unsigned short* wcat = (unsigned short*)(ws + 33554432);     //  8,388,608 B
  float* bias_sw       = (float*)(ws + 41943040);              //     16,384 B
  unsigned short* hbf  = (unsigned short*)(ws + 41959424);     //  1,048,576 B (2 parity x 2 dir)
  int* cnt             = (int*)(ws + 43008000);                //      1,024 B (8 chains, 128B stride)

  hipMemsetAsync(hbf, 0, (size_t)2*BH*2, stream);   // parity-0 h buffers = h0 = 0
  hipMemsetAsync(cnt, 0, 1024, stream);

  prep_x_k   <<<2048, 256, 0, stream>>>(x, xtr);
  prep_w_k   <<<4096, 256, 0, stream>>>(Wf, Uf, Wb, Ub, wcat);
  prep_bias_k<<<16,   256, 0, stream>>>(bf_, bb_, bias_sw);

  void* kargs[] = {(void*)&xtr, (void*)&wcat, (void*)&bias_sw,
                   (void*)&hbf, (void*)&cnt, (void*)&out};
  hipLaunchCooperativeKernel((const void*)lstm_persist_k, dim3(256), dim3(512),
                             kargs, 0, stream);

  final_k<<<1024, 256, 0, stream>>>(out);
}